// Round 2
// baseline (1216.912 us; speedup 1.0000x reference)
//
#include <hip/hip_runtime.h>
#include <math.h>

#define N_NODES 50000
#define N_EDGES 800000
#define CH 128        // IN_CH = OUT_CH = MSG_DIM = TIME_DIM = 128
#define GDIM 512      // 2 heads * 256 (G per-node vector)

// ---------------------------------------------------------------------------
// build_M: rows 0..127: M[i][f] = sum_c Wq[i][h*64+c] * We[jj][h*64+c]
// row 128 (blockIdx==128): same with bq -> gb   (fused gbias)
// ---------------------------------------------------------------------------
__global__ __launch_bounds__(256) void build_M_kernel(
    const float* __restrict__ Wq, const float* __restrict__ bq,
    const float* __restrict__ We,
    float* __restrict__ M, float* __restrict__ gb)
{
    __shared__ float wq[CH];
    const int i = blockIdx.x, t = threadIdx.x;
    const float* srcrow = (i < CH) ? (Wq + (size_t)i * CH) : bq;
    if (t < CH) wq[t] = srcrow[t];
    __syncthreads();
    float* orow = (i < CH) ? (M + (size_t)i * GDIM) : gb;
    #pragma unroll
    for (int rep = 0; rep < 2; ++rep) {
        int f  = rep * 256 + t;
        int h  = f >> 8, jj = f & 255;
        const float* wer = We + (size_t)jj * CH + h * 64;
        const float* wqr = wq + h * 64;
        float s = 0.f;
        #pragma unroll 8
        for (int c = 0; c < 64; ++c) s = fmaf(wqr[c], wer[c], s);
        orow[f] = s;
    }
}

// ---------------------------------------------------------------------------
// node_linear: Q,K,V,S = x@W+b (128 cols each), G = x@M+gb (512 cols).
// ---------------------------------------------------------------------------
__global__ __launch_bounds__(256) void node_linear_kernel(
    const float* __restrict__ x,
    const float* __restrict__ Wq, const float* __restrict__ bq,
    const float* __restrict__ Wk, const float* __restrict__ bk,
    const float* __restrict__ Wv, const float* __restrict__ bv,
    const float* __restrict__ Ws, const float* __restrict__ bs,
    const float* __restrict__ M,  const float* __restrict__ gb,
    float* __restrict__ Q, float* __restrict__ K,
    float* __restrict__ V, float* __restrict__ S, float* __restrict__ G)
{
    __shared__ float xs[64][CH];
    const int t  = threadIdx.x;
    const int n0 = blockIdx.x * 64;

    #pragma unroll
    for (int r = 0; r < 8; ++r) {
        int flat4 = r * 256 + t;        // float4 index in 64x128 tile
        int row   = flat4 >> 5;
        int c4    = (flat4 & 31) * 4;
        int gr    = n0 + row; if (gr >= N_NODES) gr = N_NODES - 1;
        *(float4*)&xs[row][c4] = *(const float4*)&x[(size_t)gr * CH + c4];
    }
    __syncthreads();

    const int tx = t & 31, ey = t >> 5;
    const int c0 = tx * 4, e0 = ey * 8;

    const float* Wp[8]   = {Wq, Wk, Wv, Ws, M, M + 128, M + 256, M + 384};
    const int    wstr[8] = {CH, CH, CH, CH, GDIM, GDIM, GDIM, GDIM};
    const float* Bp[8]   = {bq, bk, bv, bs, gb, gb + 128, gb + 256, gb + 384};
    float*       Op[8]   = {Q, K, V, S, G, G + 128, G + 256, G + 384};
    const int    ostr[8] = {CH, CH, CH, CH, GDIM, GDIM, GDIM, GDIM};

    #pragma unroll
    for (int m = 0; m < 8; ++m) {
        const float* W = Wp[m];
        const int ws_ = wstr[m];
        float4 acc[8];
        #pragma unroll
        for (int i = 0; i < 8; ++i) acc[i] = make_float4(0.f, 0.f, 0.f, 0.f);
        for (int j = 0; j < CH; ++j) {
            float4 w = *(const float4*)&W[(size_t)j * ws_ + c0];
            #pragma unroll
            for (int i = 0; i < 8; ++i) {
                float a = xs[e0 + i][j];
                acc[i].x = fmaf(a, w.x, acc[i].x);
                acc[i].y = fmaf(a, w.y, acc[i].y);
                acc[i].z = fmaf(a, w.z, acc[i].z);
                acc[i].w = fmaf(a, w.w, acc[i].w);
            }
        }
        float4 b4 = *(const float4*)&Bp[m][c0];
        float* O  = Op[m];
        const int os = ostr[m];
        #pragma unroll
        for (int i = 0; i < 8; ++i) {
            int n = n0 + e0 + i;
            if (n < N_NODES) {
                float4 r = make_float4(acc[i].x + b4.x, acc[i].y + b4.y,
                                       acc[i].z + b4.z, acc[i].w + b4.w);
                *(float4*)&O[(size_t)n * os + c0] = r;
            }
        }
    }
}

// ---------------------------------------------------------------------------
// counting sort of edges by destination node
// ---------------------------------------------------------------------------
__global__ void hist_kernel(const int* __restrict__ ei, int* __restrict__ cnt)
{
    int e = blockIdx.x * 256 + threadIdx.x;
    atomicAdd(&cnt[ei[N_EDGES + e]], 1);
}

__global__ __launch_bounds__(1024) void scan_kernel(
    const int* __restrict__ cnt, int* __restrict__ base, int* __restrict__ cursor)
{
    __shared__ int ssum[1024];
    const int t = threadIdx.x;
    const int STRIP = 49;  // 1024*49 = 50176 >= N_NODES
    const int s0 = t * STRIP;
    int sum = 0;
    for (int i = 0; i < STRIP; ++i) {
        int idx = s0 + i;
        sum += (idx < N_NODES) ? cnt[idx] : 0;
    }
    ssum[t] = sum;
    __syncthreads();
    for (int off = 1; off < 1024; off <<= 1) {
        int v = (t >= off) ? ssum[t - off] : 0;
        __syncthreads();
        ssum[t] += v;
        __syncthreads();
    }
    int run = (t > 0) ? ssum[t - 1] : 0;
    for (int i = 0; i < STRIP; ++i) {
        int idx = s0 + i;
        if (idx < N_NODES) {
            base[idx] = run; cursor[idx] = run;
            run += cnt[idx];
        }
    }
    if (t == 1023) base[N_NODES] = ssum[1023];
}

// scatter: pack (src, eid, rel_t) into one 16B record per edge.
__global__ void scatter_kernel(const int* __restrict__ ei,
                               const float* __restrict__ last_update,
                               const float* __restrict__ t_arr,
                               int* __restrict__ cursor,
                               int4* __restrict__ sedge)
{
    int e = blockIdx.x * 256 + threadIdx.x;
    int s = ei[e];
    int d = ei[N_EDGES + e];
    float rt = last_update[s] - t_arr[e];
    int pos = atomicAdd(&cursor[d], 1);
    sedge[pos] = make_int4(s, e, __float_as_int(rt), 0);
}

// ---------------------------------------------------------------------------
// sum over each independent 32-lane half; result broadcast to all lanes of
// the half.  xor1/2 quad_perm, mirror-4/8 (valid after lower steps), xor16
// via ds_swizzle.  (proven pattern from the previous wave_allsum)
// ---------------------------------------------------------------------------
__device__ __forceinline__ float half_allsum(float p) {
    p += __int_as_float(__builtin_amdgcn_update_dpp(
            0, __float_as_int(p), 0xB1, 0xF, 0xF, true));   // xor1
    p += __int_as_float(__builtin_amdgcn_update_dpp(
            0, __float_as_int(p), 0x4E, 0xF, 0xF, true));   // xor2
    p += __int_as_float(__builtin_amdgcn_update_dpp(
            0, __float_as_int(p), 0x141, 0xF, 0xF, true));  // row_half_mirror -> 8-sum
    p += __int_as_float(__builtin_amdgcn_update_dpp(
            0, __float_as_int(p), 0x140, 0xF, 0xF, true));  // row_mirror -> 16-sum
    p += __int_as_float(__builtin_amdgcn_ds_swizzle(__float_as_int(p), 0x401F)); // xor16 -> 32-sum
    return p;
}

__device__ __forceinline__ float dot4(float4 a, float4 b) {
    return fmaf(a.x, b.x, fmaf(a.y, b.y, fmaf(a.z, b.z, a.w * b.w)));
}

#define FMA4(acc, s, v) \
    acc.x = fmaf(s, v.x, acc.x); acc.y = fmaf(s, v.y, acc.y); \
    acc.z = fmaf(s, v.z, acc.z); acc.w = fmaf(s, v.w, acc.w)

#define XC4(v) \
    v.x += __shfl_xor(v.x, 32); v.y += __shfl_xor(v.y, 32); \
    v.z += __shfl_xor(v.z, 32); v.w += __shfl_xor(v.w, 32)

// ---------------------------------------------------------------------------
// gather_attn: one wave per destination node; the two 32-lane halves process
// two edges simultaneously (lane owns 4 contiguous channels, float4 loads).
// Per-head dot via masked partial + one 32-lane reduction per score.
// Unroll x2 -> 4 edges in flight per wave.
// ---------------------------------------------------------------------------
__global__ __launch_bounds__(256, 4) void gather_attn_kernel(
    const float* __restrict__ msg,
    const float* __restrict__ W_time,
    const float* __restrict__ b_time,
    const float* __restrict__ We,
    const float* __restrict__ Q, const float* __restrict__ K,
    const float* __restrict__ V, const float* __restrict__ S,
    const float* __restrict__ G,
    const int* __restrict__ base,
    const int4* __restrict__ sedge,
    float* __restrict__ out)
{
    __shared__ float wabuf[4][GDIM];   // p-weighted edge_attr sums, per head
    __shared__ float nvbuf[4][CH];     // p-weighted V sums
    __shared__ float dsh[4][2];        // softmax denominators per head
    __shared__ int   degsh[4];

    const int wv   = threadIdx.x >> 6;
    const int lane = threadIdx.x & 63;
    const int h32  = lane >> 5;        // which edge of the pair
    const int l    = lane & 31;        // channel-group id within an edge
    const int c0   = l * 4;            // lane's 4 channels
    const float mh0 = (l < 16) ? 1.f : 0.f;   // lane's channels belong to head0?
    const int n = blockIdx.x * 4 + wv;

    const float4 q4  = *(const float4*)&Q[(size_t)n * CH + c0];
    const float* gp  = G + (size_t)n * GDIM;
    const float4 gt0 = *(const float4*)&gp[c0];
    const float4 gm0 = *(const float4*)&gp[128 + c0];
    const float4 gt1 = *(const float4*)&gp[256 + c0];
    const float4 gm1 = *(const float4*)&gp[384 + c0];
    const float4 wt4 = *(const float4*)&W_time[c0];
    const float4 bt4 = *(const float4*)&b_time[c0];

    float4 waT0 = {0,0,0,0}, waM0 = {0,0,0,0};
    float4 waT1 = {0,0,0,0}, waM1 = {0,0,0,0};
    float4 nv4  = {0,0,0,0};
    float den0 = 0.f, den1 = 0.f;

    const int b0 = base[n], b1 = base[n + 1];

    for (int i = b0; i < b1; i += 4) {
        const int  iA = i + h32;
        const int  iB = i + 2 + h32;
        const bool vA = iA < b1;
        const bool vB = iB < b1;
        const int4 eA = sedge[vA ? iA : b1 - 1];
        const int4 eB = sedge[vB ? iB : b1 - 1];
        const float rtA = __int_as_float(eA.z);
        const float rtB = __int_as_float(eB.z);

        const float4 mA  = *(const float4*)&msg[(size_t)eA.y * CH + c0];
        const float4 kA  = *(const float4*)&K  [(size_t)eA.x * CH + c0];
        const float4 vA4 = *(const float4*)&V  [(size_t)eA.x * CH + c0];
        const float4 mB  = *(const float4*)&msg[(size_t)eB.y * CH + c0];
        const float4 kB  = *(const float4*)&K  [(size_t)eB.x * CH + c0];
        const float4 vB4 = *(const float4*)&V  [(size_t)eB.x * CH + c0];

        float4 etA, etB;
        etA.x = __cosf(fmaf(rtA, wt4.x, bt4.x));
        etA.y = __cosf(fmaf(rtA, wt4.y, bt4.y));
        etA.z = __cosf(fmaf(rtA, wt4.z, bt4.z));
        etA.w = __cosf(fmaf(rtA, wt4.w, bt4.w));
        etB.x = __cosf(fmaf(rtB, wt4.x, bt4.x));
        etB.y = __cosf(fmaf(rtB, wt4.y, bt4.y));
        etB.z = __cosf(fmaf(rtB, wt4.z, bt4.z));
        etB.w = __cosf(fmaf(rtB, wt4.w, bt4.w));

        const float qkA = dot4(q4, kA);
        const float qkB = dot4(q4, kB);

        float uA = fmaf(mh0,       qkA, dot4(etA, gt0) + dot4(mA, gm0));
        float wA = fmaf(1.f - mh0, qkA, dot4(etA, gt1) + dot4(mA, gm1));
        float uB = fmaf(mh0,       qkB, dot4(etB, gt0) + dot4(mB, gm0));
        float wB = fmaf(1.f - mh0, qkB, dot4(etB, gt1) + dot4(mB, gm1));

        uA = half_allsum(uA);
        wA = half_allsum(wA);
        uB = half_allsum(uB);
        wB = half_allsum(wB);

        const float p0A = vA ? __expf(uA * 0.125f) : 0.f;
        const float p1A = vA ? __expf(wA * 0.125f) : 0.f;
        const float p0B = vB ? __expf(uB * 0.125f) : 0.f;
        const float p1B = vB ? __expf(wB * 0.125f) : 0.f;

        den0 += p0A + p0B;
        den1 += p1A + p1B;

        FMA4(waT0, p0A, etA); FMA4(waT0, p0B, etB);
        FMA4(waM0, p0A, mA);  FMA4(waM0, p0B, mB);
        FMA4(waT1, p1A, etA); FMA4(waT1, p1B, etB);
        FMA4(waM1, p1A, mA);  FMA4(waM1, p1B, mB);

        const float pA = (l < 16) ? p0A : p1A;   // own-head weight
        const float pB = (l < 16) ? p0B : p1B;
        FMA4(nv4, pA, vA4);
        FMA4(nv4, pB, vB4);
    }

    // -------- combine the two edge-halves (once per node) -------------------
    XC4(waT0); XC4(waM0); XC4(waT1); XC4(waM1); XC4(nv4);
    den0 += __shfl_xor(den0, 32);
    den1 += __shfl_xor(den1, 32);

    if (h32 == 0) {
        *(float4*)&wabuf[wv][c0]       = waT0;
        *(float4*)&wabuf[wv][128 + c0] = waM0;
        *(float4*)&wabuf[wv][256 + c0] = waT1;
        *(float4*)&wabuf[wv][384 + c0] = waM1;
        *(float4*)&nvbuf[wv][c0]       = nv4;
        if (l == 0) {
            dsh[wv][0] = den0; dsh[wv][1] = den1;
            degsh[wv]  = b1 - b0;
        }
    }
    __syncthreads();

    // -------- block-cooperative We projection ------------------------------
    const int col = threadIdx.x & 127;
    const int pr  = threadIdx.x >> 7;
    const int h   = col >> 6;
    const int nA  = 2 * pr, nB = 2 * pr + 1;
    const int wo  = h * 256;

    float aA = 0.f, aB = 0.f;
    #pragma unroll 8
    for (int jj = 0; jj < 256; ++jj) {
        float w = We[(size_t)jj * CH + col];
        aA = fmaf(wabuf[nA][wo + jj], w, aA);
        aB = fmaf(wabuf[nB][wo + jj], w, aB);
    }

    {
        int node = blockIdx.x * 4 + nA;
        float r = (degsh[nA] > 0) ? (nvbuf[nA][col] + aA) / dsh[nA][h] : 0.f;
        out[(size_t)node * CH + col] = r + S[(size_t)node * CH + col];
    }
    {
        int node = blockIdx.x * 4 + nB;
        float r = (degsh[nB] > 0) ? (nvbuf[nB][col] + aB) / dsh[nB][h] : 0.f;
        out[(size_t)node * CH + col] = r + S[(size_t)node * CH + col];
    }
}

extern "C" void kernel_launch(void* const* d_in, const int* in_sizes, int n_in,
                              void* d_out, int out_size, void* d_ws, size_t ws_size,
                              hipStream_t stream) {
    const float* x           = (const float*)d_in[0];
    const float* last_update = (const float*)d_in[1];
    const float* t           = (const float*)d_in[2];
    const float* msg         = (const float*)d_in[3];
    const int*   edge_index  = (const int*)d_in[4];
    const float* W_time      = (const float*)d_in[5];
    const float* b_time      = (const float*)d_in[6];
    const float* Wq = (const float*)d_in[7];
    const float* bq = (const float*)d_in[8];
    const float* Wk = (const float*)d_in[9];
    const float* bk = (const float*)d_in[10];
    const float* Wv = (const float*)d_in[11];
    const float* bv = (const float*)d_in[12];
    const float* We = (const float*)d_in[13];
    const float* Ws = (const float*)d_in[14];
    const float* bs = (const float*)d_in[15];
    float* out = (float*)d_out;

    float* ws = (float*)d_ws;
    const size_t NC = (size_t)N_NODES * CH;
    float* Q  = ws;
    float* K  = Q + NC;
    float* V  = K + NC;
    float* S  = V + NC;
    float* G  = S + NC;                            // N*512
    float* M  = G + (size_t)N_NODES * GDIM;        // 128*512
    float* gb = M + (size_t)CH * GDIM;             // 512
    int* cnt    = (int*)(gb + GDIM);
    int* base   = cnt + N_NODES;
    int* cursor = base + N_NODES + 1;
    // align edge records to 16 bytes for int4
    size_t off = (size_t)((char*)(cursor + N_NODES) - (char*)d_ws);
    off = (off + 15) & ~(size_t)15;
    int4* sedge = (int4*)((char*)d_ws + off);

    hipMemsetAsync(cnt, 0, (size_t)N_NODES * sizeof(int), stream);

    build_M_kernel<<<CH + 1, 256, 0, stream>>>(Wq, bq, We, M, gb);

    node_linear_kernel<<<(N_NODES + 63) / 64, 256, 0, stream>>>(
        x, Wq, bq, Wk, bk, Wv, bv, Ws, bs, M, gb, Q, K, V, S, G);

    hist_kernel<<<N_EDGES / 256, 256, 0, stream>>>(edge_index, cnt);
    scan_kernel<<<1, 1024, 0, stream>>>(cnt, base, cursor);
    scatter_kernel<<<N_EDGES / 256, 256, 0, stream>>>(
        edge_index, last_update, t, cursor, sedge);

    gather_attn_kernel<<<N_NODES / 4, 256, 0, stream>>>(
        msg, W_time, b_time, We,
        Q, K, V, S, G, base, sedge, out);
}